// Round 3
// baseline (26537.851 us; speedup 1.0000x reference)
//
#include <hip/hip_runtime.h>
#include <math.h>

// ws layout (floats)
#define H0A_OFF  0            // [64][512] h0, step parity 0
#define H0B_OFF  32768        // [64][512] h0, step parity 1
#define H1_OFF   65536        // [64][512] h1
#define RH0_OFF  98304        // [64][512]
#define RH1_OFF  131072       // [64][512]
#define FLG_OFF  163840       // 4 domains x 64 u32 flags (packed, 4 lines each)
#define WS_FLOATS (163840 + 512)
#define WS_BYTES  (WS_FLOATS * 4)

// LDS row stride (words). 516 % 32 == 4: rows rgl=0..7 -> 8 distinct bank
// quads -> conflict-free b128 state reads. 516 % 4 == 0 keeps 16B alignment.
#define SROW 516

__device__ __forceinline__ void gstore(float* p, float v) {
    __hip_atomic_store(p, v, __ATOMIC_RELAXED, __HIP_MEMORY_SCOPE_AGENT);
}
__device__ __forceinline__ unsigned gloadU(const unsigned* p) {
    return __hip_atomic_load(p, __ATOMIC_RELAXED, __HIP_MEMORY_SCOPE_AGENT);
}
__device__ __forceinline__ void gstoreU(unsigned* p, unsigned v) {
    __hip_atomic_store(p, v, __ATOMIC_RELAXED, __HIP_MEMORY_SCOPE_AGENT);
}
__device__ __forceinline__ float fma4(float4 w, float4 x, float a) {
    a = fmaf(w.x, x.x, a); a = fmaf(w.y, x.y, a);
    a = fmaf(w.z, x.z, a); a = fmaf(w.w, x.w, a);
    return a;
}

// Issue 16 coherent b128 loads (64 KB region across 256 threads). Values are
// NOT valid until a vmcnt drain.
__device__ __forceinline__ void issue16(float4 t[16], const float* __restrict__ src, int tid) {
    #pragma unroll
    for (int i = 0; i < 16; ++i) {
        const float* p = src + 4 * tid + 1024 * i;
        asm volatile("global_load_dwordx4 %0, %1, off sc0 sc1"
                     : "=&v"(t[i]) : "v"(p) : "memory");
    }
}
__device__ __forceinline__ void drain_all() {
    asm volatile("s_waitcnt vmcnt(0)" ::: "memory");
}
// Wait until only the 16 NEWEST vmem ops remain outstanding (FIFO): completes
// everything issued before them. Later compiler-emitted waits can only be
// more conservative (they force extra completion), never unsafe.
__device__ __forceinline__ void drain_keep16() {
    asm volatile("s_waitcnt vmcnt(16)" ::: "memory");
}
__device__ __forceinline__ void lds_write16(float* __restrict__ buf, const float4 t[16], int tid) {
    #pragma unroll
    for (int i = 0; i < 16; ++i) {
        int f4i = tid + 256 * i;
        int row = f4i >> 7, col4 = f4i & 127;
        *(float4*)&buf[row * SROW + col4 * 4] = t[i];
    }
}

// One-hop domain barrier (64 blocks). Arrivals: per-block flag STORE into a
// packed 64-u32 array (4 cache lines, no RMW). Detection: wave 4 (tid>=256)
// polls lane-wise: own[L] >= tag AND oth[L] >= otag (cross-domain gate folded
// in; otag==0 -> auto-true). First __syncthreads drains each wave's vmem
// (HIP barrier semantics) -> all data stores for this phase are at the
// coherence point before the flag store. Tags are monotonic, never reset.
__device__ __forceinline__ void gbar(const unsigned* own, const unsigned* oth,
                                     unsigned* mine, int tid,
                                     unsigned tag, unsigned otag) {
    __syncthreads();
    if (tid == 0) gstoreU(mine, tag);
    if (tid >= 256) {
        const int L = tid - 256;
        for (;;) {
            bool ok = ((int)(gloadU(own + L) - tag) >= 0) &&
                      ((int)(gloadU(oth + L) - otag) >= 0);
            if (__ballot(ok) == ~0ull) break;
            __builtin_amdgcn_s_sleep(2);
        }
    }
    __syncthreads();
}

__global__ __launch_bounds__(320, 1) void gru_main(
    const int* __restrict__ tokens, const float* __restrict__ emb,
    const float* __restrict__ Wr0, const float* __restrict__ br0,
    const float* __restrict__ Wz0, const float* __restrict__ bz0,
    const float* __restrict__ Wh0, const float* __restrict__ bh0,
    const float* __restrict__ Wr1, const float* __restrict__ br1,
    const float* __restrict__ Wz1, const float* __restrict__ bz1,
    const float* __restrict__ Wh1, const float* __restrict__ bh1,
    float* __restrict__ ws)
{
    const int blk = blockIdx.x;
    const int tid = threadIdx.x;
    const bool comp = tid < 256;          // waves 0-3 compute; wave 4 = barrier poller

    // XCD = blk%8 = rg*4 + jl -> per-XCD weight footprint 2.75 MB (L2-resident).
    const int rg    = (blk >> 2) & 1;
    const int jl    = blk & 3;
    const int jh    = (blk >> 3) & 15;
    const int layer = blk >> 7;
    const int j     = jh * 4 + jl;
    const int ks    = (tid >> 6) & 3;     // wave = k-slice (compute waves)
    const int lane  = tid & 63;
    const int c     = lane >> 3;
    const int rgl   = lane & 7;
    const int rowbase = rg * 32;
    const int cg    = j * 8 + c;
    const int cR    = (tid >> 5) & 7;     // reducer col
    const int riR   = tid & 31;           // reducer row
    const int cgR   = j * 8 + cR;

    // Barrier domains: dom = layer*2 + rg (64 blocks each). Chains (L*,rg0)
    // and (L*,rg1) are fully independent (disjoint batch rows). L0<->L1
    // coupling is elastic via cross-domain flag checks (see gbar call sites).
    unsigned* flg = (unsigned*)(ws + FLG_OFF);
    const int dom = layer * 2 + rg;
    unsigned* ownB = flg + dom * 64;
    unsigned* othB = flg + ((layer ? 0 : 2) + rg) * 64;   // the other layer, same rg
    unsigned* mine = ownB + (jh * 4 + jl);

    const int S1 = layer ? 512 : 256;
    const int K  = S1 + 512;
    const float* WrL = layer ? Wr1 : Wr0;
    const float* WzL = layer ? Wz1 : Wz0;
    const float* WhL = layer ? Wh1 : Wh0;
    const float* wrRow = WrL + (size_t)cg * K;
    const float* wzRow = WzL + (size_t)cg * K;
    const float* whRow = WhL + (size_t)cg * K;
    const float bR = (layer ? br1 : br0)[cgR];
    const float bZ = (layer ? bz1 : bz0)[cgR];
    const float bH = (layer ? bh1 : bh0)[cgR];

    // h0 is double-buffered by step parity: L0 writes h0buf[s&1] at iter s,
    // reads h0buf[(s-1)&1] as h_prev; L1 stages h0buf[(s-1)&1] as hIn.
    const float* h0buf[2] = { ws + H0A_OFF, ws + H0B_OFF };
    float* h0bufW[2] = { ws + H0A_OFF, ws + H0B_OFF };
    float* h1p   = ws + H1_OFF;
    float* rhOwn = ws + (layer ? RH1_OFF : RH0_OFF);

    __shared__ float  bufA[32 * SROW];    // 66,048 B  (seg1 -> h_prev -> rh)
    __shared__ float  pTmp[3 * 1024];     // 12,288 B
    __shared__ float4 wLDS[3072];         // 49,152 B  seg2 weights [gate][chunk][col]

    // ---- one-time: seg2 weights (own 8 cols, 3 gates) -> LDS ----
    if (comp) {
        const float* Wb[3] = {WrL, WzL, WhL};
        for (int idx = tid; idx < 3072; idx += 256) {
            int g = idx >> 10, rem = idx & 1023, chunk = rem >> 3, c8 = rem & 7;
            wLDS[(g * 128 + chunk) * 8 + c8] =
                *(const float4*)(Wb[g] + (size_t)(j * 8 + c8) * K + S1 + 4 * chunk);
        }
    }

    const int k1  = ks * (S1 >> 2);       // seg1 wave base
    const int k2s = ks * 128;             // seg2 wave base (state coords)
    const int wch = ks * 32;              // seg2 wave base (wLDS chunk coords)

    for (int s = 0; s <= 1024; ++s) {
        const bool act = layer ? (s >= 1) : (s < 1024);
        float zv = 0.f, hp = 0.f, hx = 0.f;
        float aR[4] = {0,0,0,0}, aZ[4] = {0,0,0,0}, aH[4] = {0,0,0,0};
        float4 hpv[16];

        const float* hReadP = layer ? (const float*)h1p : h0buf[(s - 1) & 1];
        float*       hWriteP = layer ? h1p : h0bufW[s & 1];
        const float* hInP   = h0buf[(s - 1) & 1];   // L1 seg1 input

        // ---- phase A: stage seg1 (drained) + prefetch h_prev (left in flight) ----
        if (act && comp) {
            if (layer) {
                float4 t[16];
                issue16(t, hInP + rowbase * 512, tid);      // oldest 16
                issue16(hpv, hReadP + rowbase * 512, tid);  // newest 16
                drain_keep16();                             // seg1 done, hpv in flight
                lds_write16(bufA, t, tid);
            } else {
                float4 t[8];
                #pragma unroll
                for (int q = 0; q < 8; ++q) {               // emb gather (oldest)
                    int f4i = tid + 256 * q;
                    int row = f4i >> 6, col4 = f4i & 63;
                    int tok = tokens[(rowbase + row) * 1024 + s];
                    t[q] = *(const float4*)(emb + (size_t)tok * 256 + col4 * 4);
                }
                issue16(hpv, hReadP + rowbase * 512, tid);  // newest 16
                drain_keep16();                             // emb done, hpv in flight
                #pragma unroll
                for (int q = 0; q < 8; ++q) {
                    int f4i = tid + 256 * q;
                    int row = f4i >> 6, col4 = f4i & 63;
                    *(float4*)&bufA[row * SROW + col4 * 4] = t[q];
                }
            }
        }
        __syncthreads();

        // ---- dot seg1 (weights stream from L2; h_prev loads still in flight) ----
        if (act && comp) {
            const int nq1 = S1 >> 4;
            #pragma unroll 4
            for (int i = 0; i < nq1; ++i) {
                int kk = k1 + 4 * i;
                float4 w1 = *(const float4*)(wrRow + kk);
                float4 w2 = *(const float4*)(wzRow + kk);
                float4 w3 = *(const float4*)(whRow + kk);
                #pragma unroll
                for (int rr = 0; rr < 4; ++rr) {
                    float4 xv = *(const float4*)(&bufA[(rgl + 8 * rr) * SROW + kk]);
                    aR[rr] = fma4(w1, xv, aR[rr]);
                    aZ[rr] = fma4(w2, xv, aZ[rr]);
                    aH[rr] = fma4(w3, xv, aH[rr]);
                }
            }
        }
        __syncthreads();                  // all waves done reading seg1

        if (act && comp) {
            drain_all();                  // h_prev arrived during seg1 dot
            lds_write16(bufA, hpv, tid);
        }
        __syncthreads();

        // ---- dot seg2: r,z from LDS weights ----
        if (act && comp) {
            #pragma unroll 4
            for (int i = 0; i < 32; ++i) {
                int kst = k2s + 4 * i;
                float4 w1 = wLDS[(wch + i) * 8 + c];
                float4 w2 = wLDS[(128 + wch + i) * 8 + c];
                #pragma unroll
                for (int rr = 0; rr < 4; ++rr) {
                    float4 xv = *(const float4*)(&bufA[(rgl + 8 * rr) * SROW + kst]);
                    aR[rr] = fma4(w1, xv, aR[rr]);
                    aZ[rr] = fma4(w2, xv, aZ[rr]);
                }
            }
            #pragma unroll
            for (int rr = 0; rr < 4; ++rr) {
                int o = ks * 256 + c * 32 + (rgl + 8 * rr);
                pTmp[o]        = aR[rr];
                pTmp[1024 + o] = aZ[rr];
                pTmp[2048 + o] = aH[rr];
            }
        }
        __syncthreads();

        // ---- reduce + activations + publish rh ----
        if (act && comp) {
            int o = cR * 32 + riR;
            float sR = pTmp[o] + pTmp[o + 256] + pTmp[o + 512] + pTmp[o + 768];
            float sZ = pTmp[1024 + o] + pTmp[1280 + o] + pTmp[1536 + o] + pTmp[1792 + o];
            float sH = pTmp[2048 + o] + pTmp[2304 + o] + pTmp[2560 + o] + pTmp[2816 + o];
            float rv = 1.f / (1.f + expf(-(sR + bR)));
            zv = 1.f / (1.f + expf(-(sZ + bZ)));
            hx = sH;
            hp = bufA[riR * SROW + cgR];          // bufA still holds h_prev
            gstore(rhOwn + (rowbase + riR) * 512 + cgR, rv * hp);
        }

        // ---- barrier 1 (tag 2s+1), domain-internal rh exchange.
        // L0 extra gate (anti-clobber): before publishing h0[s] (which
        // overwrites parity buffer holding h0[s-2]) ensure L1 blocks passed
        // their barrier-1 of iter s-1 (tag 2s-1), i.e. finished staging
        // h0[s-2]. Needed only for s>=2.
        {
            unsigned tag  = (unsigned)(2 * s + 1);
            unsigned otag = (!layer && s >= 2) ? (unsigned)(2 * s - 1) : 0u;
            gbar(ownB, othB, mine, tid, tag, otag);
        }

        // ---- P2: stage rh, h-gate recurrent dot ----
        if (act && comp) {
            float4 t[16];
            issue16(t, rhOwn + rowbase * 512, tid);
            drain_all();
            lds_write16(bufA, t, tid);
        }
        __syncthreads();

        if (act && comp) {
            float a[4] = {0,0,0,0};
            #pragma unroll 4
            for (int i = 0; i < 32; ++i) {
                int kst = k2s + 4 * i;
                float4 w3 = wLDS[(256 + wch + i) * 8 + c];
                #pragma unroll
                for (int rr = 0; rr < 4; ++rr) {
                    float4 xv = *(const float4*)(&bufA[(rgl + 8 * rr) * SROW + kst]);
                    a[rr] = fma4(w3, xv, a[rr]);
                }
            }
            #pragma unroll
            for (int rr = 0; rr < 4; ++rr)
                pTmp[ks * 256 + c * 32 + (rgl + 8 * rr)] = a[rr];
        }
        __syncthreads();

        if (act && comp) {
            int o = cR * 32 + riR;
            float sH2 = pTmp[o] + pTmp[o + 256] + pTmp[o + 512] + pTmp[o + 768];
            float ht = tanhf(hx + sH2 + bH);
            float hn = (1.f - zv) * hp + zv * ht;
            gstore(hWriteP + (rowbase + riR) * 512 + cgR, hn);
        }

        // ---- barrier 2 (tag 2s+2), domain-internal h exchange.
        // L1 extra gate: next iter stages hIn = h0[s]; wait until all L0
        // blocks (same rg) arrived at THEIR barrier-2 of iter s (same tag) —
        // h0[s] stores drained before those flags.
        {
            unsigned tag  = (unsigned)(2 * s + 2);
            unsigned otag = layer ? tag : 0u;
            gbar(ownB, othB, mine, tid, tag, otag);
        }
    }
}

__global__ __launch_bounds__(128) void gru_fc(
    const float* __restrict__ h1f, const float* __restrict__ fcW,
    const float* __restrict__ fcb, float* __restrict__ out)
{
    int tid = threadIdx.x;
    int b = tid >> 1, cc = tid & 1;
    const float* hrow = h1f + b * 512;
    const float* wrow = fcW + cc * 512;
    float acc = 0.f;
    #pragma unroll 4
    for (int k = 0; k < 512; k += 4) {
        float4 hv = *(const float4*)(hrow + k);
        float4 wv = *(const float4*)(wrow + k);
        acc = fmaf(hv.x, wv.x, fmaf(hv.y, wv.y, fmaf(hv.z, wv.z, fmaf(hv.w, wv.w, acc))));
    }
    out[b * 2 + cc] = acc + fcb[cc];
}

extern "C" void kernel_launch(void* const* d_in, const int* in_sizes, int n_in,
                              void* d_out, int out_size, void* d_ws, size_t ws_size,
                              hipStream_t stream) {
    const int* tokens = (const int*)d_in[0];
    const float* emb = (const float*)d_in[1];
    const float* Wr0 = (const float*)d_in[2];  const float* br0 = (const float*)d_in[3];
    const float* Wz0 = (const float*)d_in[4];  const float* bz0 = (const float*)d_in[5];
    const float* Wh0 = (const float*)d_in[6];  const float* bh0 = (const float*)d_in[7];
    const float* Wr1 = (const float*)d_in[8];  const float* br1 = (const float*)d_in[9];
    const float* Wz1 = (const float*)d_in[10]; const float* bz1 = (const float*)d_in[11];
    const float* Wh1 = (const float*)d_in[12]; const float* bh1 = (const float*)d_in[13];
    const float* fcW = (const float*)d_in[14]; const float* fcb = (const float*)d_in[15];
    float* ws = (float*)d_ws;

    hipMemsetAsync(d_ws, 0, WS_BYTES, stream);

    gru_main<<<256, 320, 0, stream>>>(tokens, emb, Wr0, br0, Wz0, bz0, Wh0, bh0,
                                      Wr1, br1, Wz1, bz1, Wh1, bh1, ws);
    gru_fc<<<1, 128, 0, stream>>>(ws + H1_OFF, fcW, fcb, (float*)d_out);
}

// Round 4
// 21983.618 us; speedup vs baseline: 1.2072x; 1.2072x over previous
//
#include <hip/hip_runtime.h>
#include <math.h>

// ws layout (floats)
#define H0A_OFF  0            // [64][512] h0, step parity 0
#define H0B_OFF  32768        // [64][512] h0, step parity 1
#define H1_OFF   65536        // [64][512] h1
#define RH0_OFF  98304        // [64][512]
#define RH1_OFF  131072       // [64][512]
#define FLG_OFF  163840       // u32: arr[4 dom][64] then go[4 dom] @64B stride
#define WS_FLOATS (163840 + 512)
#define WS_BYTES  (WS_FLOATS * 4)

// LDS row stride (words). 516 % 32 == 4: rows rgl=0..7 -> 8 distinct bank
// quads -> conflict-free b128 state reads. 516 % 4 == 0 keeps 16B alignment.
#define SROW 516

__device__ __forceinline__ void gstore(float* p, float v) {
    __hip_atomic_store(p, v, __ATOMIC_RELAXED, __HIP_MEMORY_SCOPE_AGENT);
}
__device__ __forceinline__ unsigned gloadU(const unsigned* p) {
    return __hip_atomic_load(p, __ATOMIC_RELAXED, __HIP_MEMORY_SCOPE_AGENT);
}
__device__ __forceinline__ void gstoreU(unsigned* p, unsigned v) {
    __hip_atomic_store(p, v, __ATOMIC_RELAXED, __HIP_MEMORY_SCOPE_AGENT);
}
__device__ __forceinline__ float fma4(float4 w, float4 x, float a) {
    a = fmaf(w.x, x.x, a); a = fmaf(w.y, x.y, a);
    a = fmaf(w.z, x.z, a); a = fmaf(w.w, x.w, a);
    return a;
}

// Issue 16 coherent b128 loads (64 KB region across 256 threads). Values are
// NOT valid until a vmcnt drain.
__device__ __forceinline__ void issue16(float4 t[16], const float* __restrict__ src, int tid) {
    #pragma unroll
    for (int i = 0; i < 16; ++i) {
        const float* p = src + 4 * tid + 1024 * i;
        asm volatile("global_load_dwordx4 %0, %1, off sc0 sc1"
                     : "=&v"(t[i]) : "v"(p) : "memory");
    }
}
__device__ __forceinline__ void drain_all() {
    asm volatile("s_waitcnt vmcnt(0)" ::: "memory");
}
// Wait until only the 16 NEWEST vmem ops remain outstanding (FIFO): completes
// everything issued before them. Later compiler-emitted waits can only be
// more conservative (they force extra completion), never unsafe.
__device__ __forceinline__ void drain_keep16() {
    asm volatile("s_waitcnt vmcnt(16)" ::: "memory");
}
__device__ __forceinline__ void lds_write16(float* __restrict__ buf, const float4 t[16], int tid) {
    #pragma unroll
    for (int i = 0; i < 16; ++i) {
        int f4i = tid + 256 * i;
        int row = f4i >> 7, col4 = f4i & 127;
        *(float4*)&buf[row * SROW + col4 * 4] = t[i];
    }
}

// Per-domain 2-hop barrier (64 blocks), baseline poll profile:
// arrivals = per-block flag STORE to arr[dom][idx] (distinct addrs, 4 lines);
// detection = ONE aggregator wave (wave 4 of the dom's j==0 block) polls the
// 64 arr flags (1 per lane) AND the other layer's go-gate, then publishes
// go[dom]=tag; members poll go[dom] with a single scalar load.
// Cross-layer gate folded into go publication: go[dom]>=tag implies all own
// arrivals >= tag and goOth >= otag(tag). First __syncthreads drains each
// wave's vmem (HIP barrier semantics) -> data stores for this phase are at
// the coherence point before the arrival store. Tags monotonic, never reset.
__device__ __forceinline__ void gbar(unsigned* arrD, unsigned* goOwn,
                                     const unsigned* goOth, int myIdx, bool agg,
                                     int tid, unsigned tag, unsigned otag) {
    __syncthreads();
    if (tid >= 256) {
        if (agg) {
            const int L = tid - 256;
            for (;;) {
                bool ok = ((int)(gloadU(arrD + L) - tag) >= 0) &&
                          ((int)(gloadU(goOth) - otag) >= 0);
                if (__ballot(ok) == ~0ull) break;
                __builtin_amdgcn_s_sleep(2);
            }
            if (tid == 256) gstoreU(goOwn, tag);
        }
    } else if (tid == 0) {
        gstoreU(arrD + myIdx, tag);
        while ((int)(gloadU(goOwn) - tag) < 0)
            __builtin_amdgcn_s_sleep(2);
    }
    __syncthreads();
}

__global__ __launch_bounds__(320, 1) void gru_main(
    const int* __restrict__ tokens, const float* __restrict__ emb,
    const float* __restrict__ Wr0, const float* __restrict__ br0,
    const float* __restrict__ Wz0, const float* __restrict__ bz0,
    const float* __restrict__ Wh0, const float* __restrict__ bh0,
    const float* __restrict__ Wr1, const float* __restrict__ br1,
    const float* __restrict__ Wz1, const float* __restrict__ bz1,
    const float* __restrict__ Wh1, const float* __restrict__ bh1,
    float* __restrict__ ws)
{
    const int blk = blockIdx.x;
    const int tid = threadIdx.x;
    const bool comp = tid < 256;          // waves 0-3 compute; wave 4 = aggregator duty

    // XCD = blk%8 = rg*4 + jl -> per-XCD weight footprint L2-resident.
    const int rg    = (blk >> 2) & 1;
    const int jl    = blk & 3;
    const int jh    = (blk >> 3) & 15;
    const int layer = blk >> 7;
    const int j     = jh * 4 + jl;
    const int ks    = (tid >> 6) & 3;     // wave = k-slice (compute waves)
    const int lane  = tid & 63;
    const int c     = lane >> 3;
    const int rgl   = lane & 7;
    const int rowbase = rg * 32;
    const int cg    = j * 8 + c;
    const int cR    = (tid >> 5) & 7;     // reducer col
    const int riR   = tid & 31;           // reducer row
    const int cgR   = j * 8 + cR;

    // Barrier domains: dom = layer*2 + rg (64 blocks each); (L*,rg0)/(L*,rg1)
    // chains are fully independent (disjoint batch rows). L0<->L1 coupling is
    // elastic via go-gates (see gbar call sites) + h0 parity double-buffer.
    unsigned* flg  = (unsigned*)(ws + FLG_OFF);
    const int dom  = layer * 2 + rg;
    const int odom = (layer ? 0 : 2) + rg;     // other layer, same rg
    unsigned* arrD  = flg + dom * 64;
    unsigned* goOwn = flg + 256 + dom * 16;    // 64 B apart
    unsigned* goOth = flg + 256 + odom * 16;
    const bool agg  = (j == 0);                // one aggregator block per domain

    const int S1 = layer ? 512 : 256;
    const int K  = S1 + 512;
    const float* WrL = layer ? Wr1 : Wr0;
    const float* WzL = layer ? Wz1 : Wz0;
    const float* WhL = layer ? Wh1 : Wh0;
    const float* wrRow = WrL + (size_t)cg * K;
    const float* wzRow = WzL + (size_t)cg * K;
    const float* whRow = WhL + (size_t)cg * K;
    const float bR = (layer ? br1 : br0)[cgR];
    const float bZ = (layer ? bz1 : bz0)[cgR];
    const float bH = (layer ? bh1 : bh0)[cgR];

    // h0 double-buffered by step parity: L0 writes h0buf[s&1] at iter s, reads
    // h0buf[(s-1)&1]; L1 stages h0buf[(s-1)&1] as hIn. Gives L0/L1 1-step slack.
    const float* h0buf[2] = { ws + H0A_OFF, ws + H0B_OFF };
    float* h0bufW[2] = { ws + H0A_OFF, ws + H0B_OFF };
    float* h1p   = ws + H1_OFF;
    float* rhOwn = ws + (layer ? RH1_OFF : RH0_OFF);

    __shared__ float  bufA[32 * SROW];    // 66,048 B  (seg1 -> h_prev -> rh)
    __shared__ float  pTmp[3 * 1024];     // 12,288 B
    __shared__ float4 wLDS[3072];         // 49,152 B  seg2 weights [gate][chunk][col]

    // ---- one-time: seg2 weights (own 8 cols, 3 gates) -> LDS ----
    if (comp) {
        const float* Wb[3] = {WrL, WzL, WhL};
        for (int idx = tid; idx < 3072; idx += 256) {
            int g = idx >> 10, rem = idx & 1023, chunk = rem >> 3, c8 = rem & 7;
            wLDS[(g * 128 + chunk) * 8 + c8] =
                *(const float4*)(Wb[g] + (size_t)(j * 8 + c8) * K + S1 + 4 * chunk);
        }
    }

    const int k1  = ks * (S1 >> 2);       // seg1 wave base
    const int k2s = ks * 128;             // seg2 wave base (state coords)
    const int wch = ks * 32;              // seg2 wave base (wLDS chunk coords)

    for (int s = 0; s <= 1024; ++s) {
        const bool act = layer ? (s >= 1) : (s < 1024);
        float zv = 0.f, hp = 0.f, hx = 0.f;
        float aR[4] = {0,0,0,0}, aZ[4] = {0,0,0,0}, aH[4] = {0,0,0,0};
        float4 hpv[16];

        const float* hReadP  = layer ? (const float*)h1p : h0buf[(s - 1) & 1];
        float*       hWriteP = layer ? h1p : h0bufW[s & 1];
        const float* hInP    = h0buf[(s - 1) & 1];   // L1 seg1 input

        // ---- phase A: stage seg1 (drained) + prefetch h_prev (left in flight) ----
        if (act && comp) {
            if (layer) {
                float4 t[16];
                issue16(t, hInP + rowbase * 512, tid);      // oldest 16
                issue16(hpv, hReadP + rowbase * 512, tid);  // newest 16
                drain_keep16();                             // seg1 done, hpv in flight
                lds_write16(bufA, t, tid);
            } else {
                float4 t[8];
                #pragma unroll
                for (int q = 0; q < 8; ++q) {               // emb gather (oldest)
                    int f4i = tid + 256 * q;
                    int row = f4i >> 6, col4 = f4i & 63;
                    int tok = tokens[(rowbase + row) * 1024 + s];
                    t[q] = *(const float4*)(emb + (size_t)tok * 256 + col4 * 4);
                }
                issue16(hpv, hReadP + rowbase * 512, tid);  // newest 16
                drain_keep16();                             // emb done, hpv in flight
                #pragma unroll
                for (int q = 0; q < 8; ++q) {
                    int f4i = tid + 256 * q;
                    int row = f4i >> 6, col4 = f4i & 63;
                    *(float4*)&bufA[row * SROW + col4 * 4] = t[q];
                }
            }
        }
        __syncthreads();

        // ---- dot seg1 (weights stream from L2; h_prev loads still in flight) ----
        if (act && comp) {
            const int nq1 = S1 >> 4;
            #pragma unroll 4
            for (int i = 0; i < nq1; ++i) {
                int kk = k1 + 4 * i;
                float4 w1 = *(const float4*)(wrRow + kk);
                float4 w2 = *(const float4*)(wzRow + kk);
                float4 w3 = *(const float4*)(whRow + kk);
                #pragma unroll
                for (int rr = 0; rr < 4; ++rr) {
                    float4 xv = *(const float4*)(&bufA[(rgl + 8 * rr) * SROW + kk]);
                    aR[rr] = fma4(w1, xv, aR[rr]);
                    aZ[rr] = fma4(w2, xv, aZ[rr]);
                    aH[rr] = fma4(w3, xv, aH[rr]);
                }
            }
        }
        __syncthreads();                  // all waves done reading seg1

        if (act && comp) {
            drain_all();                  // h_prev arrived during seg1 dot
            lds_write16(bufA, hpv, tid);
        }
        __syncthreads();

        // ---- dot seg2: r,z from LDS weights ----
        if (act && comp) {
            #pragma unroll 4
            for (int i = 0; i < 32; ++i) {
                int kst = k2s + 4 * i;
                float4 w1 = wLDS[(wch + i) * 8 + c];
                float4 w2 = wLDS[(128 + wch + i) * 8 + c];
                #pragma unroll
                for (int rr = 0; rr < 4; ++rr) {
                    float4 xv = *(const float4*)(&bufA[(rgl + 8 * rr) * SROW + kst]);
                    aR[rr] = fma4(w1, xv, aR[rr]);
                    aZ[rr] = fma4(w2, xv, aZ[rr]);
                }
            }
            #pragma unroll
            for (int rr = 0; rr < 4; ++rr) {
                int o = ks * 256 + c * 32 + (rgl + 8 * rr);
                pTmp[o]        = aR[rr];
                pTmp[1024 + o] = aZ[rr];
                pTmp[2048 + o] = aH[rr];
            }
        }
        __syncthreads();

        // ---- reduce + activations + publish rh ----
        if (act && comp) {
            int o = cR * 32 + riR;
            float sR = pTmp[o] + pTmp[o + 256] + pTmp[o + 512] + pTmp[o + 768];
            float sZ = pTmp[1024 + o] + pTmp[1280 + o] + pTmp[1536 + o] + pTmp[1792 + o];
            float sH = pTmp[2048 + o] + pTmp[2304 + o] + pTmp[2560 + o] + pTmp[2816 + o];
            float rv = 1.f / (1.f + expf(-(sR + bR)));
            zv = 1.f / (1.f + expf(-(sZ + bZ)));
            hx = sH;
            hp = bufA[riR * SROW + cgR];          // bufA still holds h_prev
            gstore(rhOwn + (rowbase + riR) * 512 + cgR, rv * hp);
        }

        // ---- barrier 1 (tag 2s+1), domain-internal rh exchange.
        // L0 anti-clobber gate: before publishing h0[s] (overwrites parity
        // buffer holding h0[s-2]) all L1 blocks (same rg) must have passed
        // their b1 of iter s-1 (tag 2s-1), i.e. finished staging h0[s-2].
        gbar(arrD, goOwn, goOth, j, agg, tid, (unsigned)(2 * s + 1),
             (!layer && s >= 2) ? (unsigned)(2 * s - 1) : 0u);

        // ---- P2: stage rh, h-gate recurrent dot ----
        if (act && comp) {
            float4 t[16];
            issue16(t, rhOwn + rowbase * 512, tid);
            drain_all();
            lds_write16(bufA, t, tid);
        }
        __syncthreads();

        if (act && comp) {
            float a[4] = {0,0,0,0};
            #pragma unroll 4
            for (int i = 0; i < 32; ++i) {
                int kst = k2s + 4 * i;
                float4 w3 = wLDS[(256 + wch + i) * 8 + c];
                #pragma unroll
                for (int rr = 0; rr < 4; ++rr) {
                    float4 xv = *(const float4*)(&bufA[(rgl + 8 * rr) * SROW + kst]);
                    a[rr] = fma4(w3, xv, a[rr]);
                }
            }
            #pragma unroll
            for (int rr = 0; rr < 4; ++rr)
                pTmp[ks * 256 + c * 32 + (rgl + 8 * rr)] = a[rr];
        }
        __syncthreads();

        if (act && comp) {
            int o = cR * 32 + riR;
            float sH2 = pTmp[o] + pTmp[o + 256] + pTmp[o + 512] + pTmp[o + 768];
            float ht = tanhf(hx + sH2 + bH);
            float hn = (1.f - zv) * hp + zv * ht;
            gstore(hWriteP + (rowbase + riR) * 512 + cgR, hn);
        }

        // ---- barrier 2 (tag 2s+2), domain-internal h exchange.
        // L1 gate: next iter stages hIn = h0[s]; all L0 blocks (same rg) must
        // have arrived at THEIR b2 of iter s (same tag) - h0[s] stores are
        // drained before those arrival flags.
        gbar(arrD, goOwn, goOth, j, agg, tid, (unsigned)(2 * s + 2),
             layer ? (unsigned)(2 * s + 2) : 0u);
    }
}

__global__ __launch_bounds__(128) void gru_fc(
    const float* __restrict__ h1f, const float* __restrict__ fcW,
    const float* __restrict__ fcb, float* __restrict__ out)
{
    int tid = threadIdx.x;
    int b = tid >> 1, cc = tid & 1;
    const float* hrow = h1f + b * 512;
    const float* wrow = fcW + cc * 512;
    float acc = 0.f;
    #pragma unroll 4
    for (int k = 0; k < 512; k += 4) {
        float4 hv = *(const float4*)(hrow + k);
        float4 wv = *(const float4*)(wrow + k);
        acc = fmaf(hv.x, wv.x, fmaf(hv.y, wv.y, fmaf(hv.z, wv.z, fmaf(hv.w, wv.w, acc))));
    }
    out[b * 2 + cc] = acc + fcb[cc];
}

extern "C" void kernel_launch(void* const* d_in, const int* in_sizes, int n_in,
                              void* d_out, int out_size, void* d_ws, size_t ws_size,
                              hipStream_t stream) {
    const int* tokens = (const int*)d_in[0];
    const float* emb = (const float*)d_in[1];
    const float* Wr0 = (const float*)d_in[2];  const float* br0 = (const float*)d_in[3];
    const float* Wz0 = (const float*)d_in[4];  const float* bz0 = (const float*)d_in[5];
    const float* Wh0 = (const float*)d_in[6];  const float* bh0 = (const float*)d_in[7];
    const float* Wr1 = (const float*)d_in[8];  const float* br1 = (const float*)d_in[9];
    const float* Wz1 = (const float*)d_in[10]; const float* bz1 = (const float*)d_in[11];
    const float* Wh1 = (const float*)d_in[12]; const float* bh1 = (const float*)d_in[13];
    const float* fcW = (const float*)d_in[14]; const float* fcb = (const float*)d_in[15];
    float* ws = (float*)d_ws;

    hipMemsetAsync(d_ws, 0, WS_BYTES, stream);

    gru_main<<<256, 320, 0, stream>>>(tokens, emb, Wr0, br0, Wz0, bz0, Wh0, bh0,
                                      Wr1, br1, Wz1, bz1, Wh1, bh1, ws);
    gru_fc<<<1, 128, 0, stream>>>(ws + H1_OFF, fcW, fcb, (float*)d_out);
}

// Round 5
// 18334.868 us; speedup vs baseline: 1.4474x; 1.1990x over previous
//
#include <hip/hip_runtime.h>
#include <math.h>

// ws layout (floats)
#define H0A_OFF  0            // [64][512] h0, step parity 0
#define H0B_OFF  32768        // [64][512] h0, step parity 1
#define H1_OFF   65536        // [64][512] h1
#define RH0_OFF  98304        // [64][512]
#define RH1_OFF  131072       // [64][512]
#define FLG_OFF  163840       // u32: arr[4 dom][64] then go[4 dom] @64B stride
#define WS_FLOATS (163840 + 512)
#define WS_BYTES  (WS_FLOATS * 4)

// LDS row stride (words). 516 % 32 == 4: rows rgl=0..7 -> 8 distinct bank
// quads -> conflict-free b128 state reads. 516 % 4 == 0 keeps 16B alignment.
#define SROW 516

__device__ __forceinline__ void gstore(float* p, float v) {
    __hip_atomic_store(p, v, __ATOMIC_RELAXED, __HIP_MEMORY_SCOPE_AGENT);
}
__device__ __forceinline__ unsigned gloadU(const unsigned* p) {
    return __hip_atomic_load(p, __ATOMIC_RELAXED, __HIP_MEMORY_SCOPE_AGENT);
}
__device__ __forceinline__ void gstoreU(unsigned* p, unsigned v) {
    __hip_atomic_store(p, v, __ATOMIC_RELAXED, __HIP_MEMORY_SCOPE_AGENT);
}
__device__ __forceinline__ float fma4(float4 w, float4 x, float a) {
    a = fmaf(w.x, x.x, a); a = fmaf(w.y, x.y, a);
    a = fmaf(w.z, x.z, a); a = fmaf(w.w, x.w, a);
    return a;
}

// Issue 8 coherent b128 loads (64 KB region across 512 threads). Values are
// NOT valid until a vmcnt drain.
__device__ __forceinline__ void issue8(float4 t[8], const float* __restrict__ src, int tid) {
    #pragma unroll
    for (int i = 0; i < 8; ++i) {
        const float* p = src + 4 * tid + 2048 * i;
        asm volatile("global_load_dwordx4 %0, %1, off sc0 sc1"
                     : "=&v"(t[i]) : "v"(p) : "memory");
    }
}
__device__ __forceinline__ void drain_all() {
    asm volatile("s_waitcnt vmcnt(0)" ::: "memory");
}
// Wait until only the 8 NEWEST vmem ops remain outstanding (FIFO): completes
// everything issued before them. Later compiler-emitted waits can only be
// more conservative (they force extra completion), never unsafe.
__device__ __forceinline__ void drain_keep8() {
    asm volatile("s_waitcnt vmcnt(8)" ::: "memory");
}
__device__ __forceinline__ void lds_write8(float* __restrict__ buf, const float4 t[8], int tid) {
    #pragma unroll
    for (int i = 0; i < 8; ++i) {
        int f4i = tid + 512 * i;
        int row = f4i >> 7, col4 = f4i & 127;
        *(float4*)&buf[row * SROW + col4 * 4] = t[i];
    }
}

// Per-domain 2-hop barrier (64 blocks):
// arrivals = per-block flag STORE to arr[dom][idx] (distinct addrs, 4 lines);
// detection = ONE aggregator wave (wave 8 of the dom's j==0 block) polls the
// 64 arr flags (1 per lane) AND the other layer's go-gate, then publishes
// go[dom]=tag; members poll go[dom] with a single scalar load.
// Cross-layer gate folded into go publication: go[dom]>=tag implies all own
// arrivals >= tag and goOth >= otag(tag). First __syncthreads drains each
// wave's vmem (HIP barrier semantics) -> data stores for this phase are at
// the coherence point before the arrival store. Tags monotonic, never reset.
__device__ __forceinline__ void gbar(unsigned* arrD, unsigned* goOwn,
                                     const unsigned* goOth, int myIdx, bool agg,
                                     int tid, unsigned tag, unsigned otag) {
    __syncthreads();
    if (tid >= 512) {
        if (agg) {
            const int L = tid - 512;
            for (;;) {
                bool ok = ((int)(gloadU(arrD + L) - tag) >= 0) &&
                          ((int)(gloadU(goOth) - otag) >= 0);
                if (__ballot(ok) == ~0ull) break;
                __builtin_amdgcn_s_sleep(2);
            }
            if (tid == 512) gstoreU(goOwn, tag);
        }
    } else if (tid == 0) {
        gstoreU(arrD + myIdx, tag);
        while ((int)(gloadU(goOwn) - tag) < 0)
            __builtin_amdgcn_s_sleep(2);
    }
    __syncthreads();
}

__global__ __launch_bounds__(576, 1) void gru_main(
    const int* __restrict__ tokens, const float* __restrict__ emb,
    const float* __restrict__ Wr0, const float* __restrict__ br0,
    const float* __restrict__ Wz0, const float* __restrict__ bz0,
    const float* __restrict__ Wh0, const float* __restrict__ bh0,
    const float* __restrict__ Wr1, const float* __restrict__ br1,
    const float* __restrict__ Wz1, const float* __restrict__ bz1,
    const float* __restrict__ Wh1, const float* __restrict__ bh1,
    float* __restrict__ ws)
{
    const int blk = blockIdx.x;
    const int tid = threadIdx.x;
    const bool comp = tid < 512;          // waves 0-7 compute; wave 8 = aggregator duty

    // XCD = blk%8 = rg*4 + jl -> per-XCD weight footprint L2-resident.
    const int rg    = (blk >> 2) & 1;
    const int jl    = blk & 3;
    const int jh    = (blk >> 3) & 15;
    const int layer = blk >> 7;
    const int j     = jh * 4 + jl;
    const int ks    = (tid >> 6) & 7;     // wave = k-slice (compute waves)
    const int lane  = tid & 63;
    const int c     = lane >> 3;
    const int rgl   = lane & 7;
    const int rowbase = rg * 32;
    const int cg    = j * 8 + c;
    const int cR    = (tid >> 5) & 7;     // reducer col (tid<256 only)
    const int riR   = tid & 31;           // reducer row
    const int cgR   = j * 8 + cR;

    // Barrier domains: dom = layer*2 + rg (64 blocks each); (L*,rg0)/(L*,rg1)
    // chains are fully independent (disjoint batch rows). L0<->L1 coupling is
    // elastic via go-gates (see gbar call sites) + h0 parity double-buffer.
    unsigned* flg  = (unsigned*)(ws + FLG_OFF);
    const int dom  = layer * 2 + rg;
    const int odom = (layer ? 0 : 2) + rg;     // other layer, same rg
    unsigned* arrD  = flg + dom * 64;
    unsigned* goOwn = flg + 256 + dom * 16;    // 64 B apart
    unsigned* goOth = flg + 256 + odom * 16;
    const bool agg  = (j == 0);                // one aggregator block per domain

    const int S1 = layer ? 512 : 256;
    const int K  = S1 + 512;
    const float* WrL = layer ? Wr1 : Wr0;
    const float* WzL = layer ? Wz1 : Wz0;
    const float* WhL = layer ? Wh1 : Wh0;
    const float* wrRow = WrL + (size_t)cg * K;
    const float* wzRow = WzL + (size_t)cg * K;
    const float* whRow = WhL + (size_t)cg * K;
    const float bR = (layer ? br1 : br0)[cgR];
    const float bZ = (layer ? bz1 : bz0)[cgR];
    const float bH = (layer ? bh1 : bh0)[cgR];

    // h0 double-buffered by step parity: L0 writes h0buf[s&1] at iter s, reads
    // h0buf[(s-1)&1]; L1 stages h0buf[(s-1)&1] as hIn. Gives L0/L1 1-step slack.
    const float* h0buf[2] = { ws + H0A_OFF, ws + H0B_OFF };
    float* h0bufW[2] = { ws + H0A_OFF, ws + H0B_OFF };
    float* h1p   = ws + H1_OFF;
    float* rhOwn = ws + (layer ? RH1_OFF : RH0_OFF);

    __shared__ float  bufA[32 * SROW];    // 66,048 B  (seg1 -> h_prev -> rh)
    __shared__ float  pTmp[3 * 2048];     // 24,576 B  (8 k-slices x 256 outs x 3 gates)
    __shared__ float4 wLDS[3072];         // 49,152 B  seg2 weights [gate][chunk][col]

    // ---- one-time: seg2 weights (own 8 cols, 3 gates) -> LDS ----
    if (comp) {
        const float* Wb[3] = {WrL, WzL, WhL};
        for (int idx = tid; idx < 3072; idx += 512) {
            int g = idx >> 10, rem = idx & 1023, chunk = rem >> 3, c8 = rem & 7;
            wLDS[(g * 128 + chunk) * 8 + c8] =
                *(const float4*)(Wb[g] + (size_t)(j * 8 + c8) * K + S1 + 4 * chunk);
        }
    }

    const int k1  = ks * (S1 >> 3);       // seg1 wave base (8-way k-split)
    const int k2s = ks * 64;              // seg2 wave base (state coords)
    const int wch = ks * 16;              // seg2 wave base (wLDS chunk coords)

    for (int s = 0; s <= 1024; ++s) {
        const bool act = layer ? (s >= 1) : (s < 1024);
        float zv = 0.f, hp = 0.f, hx = 0.f;
        float aR[4] = {0,0,0,0}, aZ[4] = {0,0,0,0}, aH[4] = {0,0,0,0};
        float4 hpv[8];

        const float* hReadP  = layer ? (const float*)h1p : h0buf[(s - 1) & 1];
        float*       hWriteP = layer ? h1p : h0bufW[s & 1];
        const float* hInP    = h0buf[(s - 1) & 1];   // L1 seg1 input

        // ---- phase A: stage seg1 (drained) + prefetch h_prev (left in flight) ----
        if (act && comp) {
            if (layer) {
                float4 t[8];
                issue8(t, hInP + rowbase * 512, tid);      // oldest 8
                issue8(hpv, hReadP + rowbase * 512, tid);  // newest 8
                drain_keep8();                             // seg1 done, hpv in flight
                lds_write8(bufA, t, tid);
            } else {
                float4 t[4];
                #pragma unroll
                for (int q = 0; q < 4; ++q) {              // emb gather (oldest)
                    int f4i = tid + 512 * q;
                    int row = f4i >> 6, col4 = f4i & 63;
                    int tok = tokens[(rowbase + row) * 1024 + s];
                    t[q] = *(const float4*)(emb + (size_t)tok * 256 + col4 * 4);
                }
                issue8(hpv, hReadP + rowbase * 512, tid);  // newest 8
                drain_keep8();                             // emb done, hpv in flight
                #pragma unroll
                for (int q = 0; q < 4; ++q) {
                    int f4i = tid + 512 * q;
                    int row = f4i >> 6, col4 = f4i & 63;
                    *(float4*)&bufA[row * SROW + col4 * 4] = t[q];
                }
            }
        }
        __syncthreads();

        // ---- dot seg1 (weights stream from L2; h_prev loads still in flight) ----
        if (act && comp) {
            const int nq1 = S1 >> 5;
            #pragma unroll 4
            for (int i = 0; i < nq1; ++i) {
                int kk = k1 + 4 * i;
                float4 w1 = *(const float4*)(wrRow + kk);
                float4 w2 = *(const float4*)(wzRow + kk);
                float4 w3 = *(const float4*)(whRow + kk);
                #pragma unroll
                for (int rr = 0; rr < 4; ++rr) {
                    float4 xv = *(const float4*)(&bufA[(rgl + 8 * rr) * SROW + kk]);
                    aR[rr] = fma4(w1, xv, aR[rr]);
                    aZ[rr] = fma4(w2, xv, aZ[rr]);
                    aH[rr] = fma4(w3, xv, aH[rr]);
                }
            }
        }
        __syncthreads();                  // all waves done reading seg1

        if (act && comp) {
            drain_all();                  // h_prev arrived during seg1 dot
            lds_write8(bufA, hpv, tid);
        }
        __syncthreads();

        // ---- dot seg2: r,z from LDS weights ----
        if (act && comp) {
            #pragma unroll 4
            for (int i = 0; i < 16; ++i) {
                int kst = k2s + 4 * i;
                float4 w1 = wLDS[(wch + i) * 8 + c];
                float4 w2 = wLDS[(128 + wch + i) * 8 + c];
                #pragma unroll
                for (int rr = 0; rr < 4; ++rr) {
                    float4 xv = *(const float4*)(&bufA[(rgl + 8 * rr) * SROW + kst]);
                    aR[rr] = fma4(w1, xv, aR[rr]);
                    aZ[rr] = fma4(w2, xv, aZ[rr]);
                }
            }
            #pragma unroll
            for (int rr = 0; rr < 4; ++rr) {
                int o = ks * 256 + c * 32 + (rgl + 8 * rr);
                pTmp[o]        = aR[rr];
                pTmp[2048 + o] = aZ[rr];
                pTmp[4096 + o] = aH[rr];
            }
        }
        __syncthreads();

        // ---- reduce + activations + publish rh (256 reducer threads) ----
        if (act && tid < 256) {
            int o = cR * 32 + riR;
            float sR = 0.f, sZ = 0.f, sH = 0.f;
            #pragma unroll
            for (int p = 0; p < 8; ++p) {
                sR += pTmp[o + 256 * p];
                sZ += pTmp[2048 + o + 256 * p];
                sH += pTmp[4096 + o + 256 * p];
            }
            float rv = 1.f / (1.f + expf(-(sR + bR)));
            zv = 1.f / (1.f + expf(-(sZ + bZ)));
            hx = sH;
            hp = bufA[riR * SROW + cgR];          // bufA still holds h_prev
            gstore(rhOwn + (rowbase + riR) * 512 + cgR, rv * hp);
        }

        // ---- barrier 1 (tag 2s+1), domain-internal rh exchange.
        // L0 anti-clobber gate: before publishing h0[s] (overwrites parity
        // buffer holding h0[s-2]) all L1 blocks (same rg) must have passed
        // their b1 of iter s-1 (tag 2s-1), i.e. finished staging h0[s-2].
        gbar(arrD, goOwn, goOth, j, agg, tid, (unsigned)(2 * s + 1),
             (!layer && s >= 2) ? (unsigned)(2 * s - 1) : 0u);

        // ---- P2: stage rh, h-gate recurrent dot ----
        if (act && comp) {
            float4 t[8];
            issue8(t, rhOwn + rowbase * 512, tid);
            drain_all();
            lds_write8(bufA, t, tid);
        }
        __syncthreads();

        if (act && comp) {
            float a[4] = {0,0,0,0};
            #pragma unroll 4
            for (int i = 0; i < 16; ++i) {
                int kst = k2s + 4 * i;
                float4 w3 = wLDS[(256 + wch + i) * 8 + c];
                #pragma unroll
                for (int rr = 0; rr < 4; ++rr) {
                    float4 xv = *(const float4*)(&bufA[(rgl + 8 * rr) * SROW + kst]);
                    a[rr] = fma4(w3, xv, a[rr]);
                }
            }
            #pragma unroll
            for (int rr = 0; rr < 4; ++rr)
                pTmp[ks * 256 + c * 32 + (rgl + 8 * rr)] = a[rr];
        }
        __syncthreads();

        if (act && tid < 256) {
            int o = cR * 32 + riR;
            float sH2 = 0.f;
            #pragma unroll
            for (int p = 0; p < 8; ++p) sH2 += pTmp[o + 256 * p];
            float ht = tanhf(hx + sH2 + bH);
            float hn = (1.f - zv) * hp + zv * ht;
            gstore(hWriteP + (rowbase + riR) * 512 + cgR, hn);
        }

        // ---- barrier 2 (tag 2s+2), domain-internal h exchange.
        // L1 gate: next iter stages hIn = h0[s]; all L0 blocks (same rg) must
        // have arrived at THEIR b2 of iter s (same tag) - h0[s] stores are
        // drained before those arrival flags.
        gbar(arrD, goOwn, goOth, j, agg, tid, (unsigned)(2 * s + 2),
             layer ? (unsigned)(2 * s + 2) : 0u);
    }
}

__global__ __launch_bounds__(128) void gru_fc(
    const float* __restrict__ h1f, const float* __restrict__ fcW,
    const float* __restrict__ fcb, float* __restrict__ out)
{
    int tid = threadIdx.x;
    int b = tid >> 1, cc = tid & 1;
    const float* hrow = h1f + b * 512;
    const float* wrow = fcW + cc * 512;
    float acc = 0.f;
    #pragma unroll 4
    for (int k = 0; k < 512; k += 4) {
        float4 hv = *(const float4*)(hrow + k);
        float4 wv = *(const float4*)(wrow + k);
        acc = fmaf(hv.x, wv.x, fmaf(hv.y, wv.y, fmaf(hv.z, wv.z, fmaf(hv.w, wv.w, acc))));
    }
    out[b * 2 + cc] = acc + fcb[cc];
}

extern "C" void kernel_launch(void* const* d_in, const int* in_sizes, int n_in,
                              void* d_out, int out_size, void* d_ws, size_t ws_size,
                              hipStream_t stream) {
    const int* tokens = (const int*)d_in[0];
    const float* emb = (const float*)d_in[1];
    const float* Wr0 = (const float*)d_in[2];  const float* br0 = (const float*)d_in[3];
    const float* Wz0 = (const float*)d_in[4];  const float* bz0 = (const float*)d_in[5];
    const float* Wh0 = (const float*)d_in[6];  const float* bh0 = (const float*)d_in[7];
    const float* Wr1 = (const float*)d_in[8];  const float* br1 = (const float*)d_in[9];
    const float* Wz1 = (const float*)d_in[10]; const float* bz1 = (const float*)d_in[11];
    const float* Wh1 = (const float*)d_in[12]; const float* bh1 = (const float*)d_in[13];
    const float* fcW = (const float*)d_in[14]; const float* fcb = (const float*)d_in[15];
    float* ws = (float*)d_ws;

    hipMemsetAsync(d_ws, 0, WS_BYTES, stream);

    gru_main<<<256, 576, 0, stream>>>(tokens, emb, Wr0, br0, Wz0, bz0, Wh0, bh0,
                                      Wr1, br1, Wz1, bz1, Wh1, bh1, ws);
    gru_fc<<<1, 128, 0, stream>>>(ws + H1_OFF, fcW, fcb, (float*)d_out);
}